// Round 1
// baseline (318.827 us; speedup 1.0000x reference)
//
#include <hip/hip_runtime.h>
#include <hip/hip_bf16.h>

#define B_ 4
#define C_ 256
#define S_ 4096
#define NH_ 4
#define HD_ 64

typedef __attribute__((ext_vector_type(8))) short short8;
typedef __attribute__((ext_vector_type(4))) short short4v;
typedef __attribute__((ext_vector_type(4))) float f32x4;

static __device__ __forceinline__ short f2bf(float f) {
  unsigned u = __builtin_bit_cast(unsigned, f);
  u += 0x7fffu + ((u >> 16) & 1u);
  return (short)(u >> 16);
}
static __device__ __forceinline__ float bf2f(short h) {
  unsigned u = ((unsigned)(unsigned short)h) << 16;
  return __builtin_bit_cast(float, u);
}

// ---------------- GroupNorm stats: one block per (b,g) ----------------
__global__ __launch_bounds__(256) void k_gn_stats(const float* __restrict__ x,
                                                  float* __restrict__ stats) {
  int bg = blockIdx.x;  // b*8+g
  const float* p = x + (size_t)bg * (32 * S_);  // contiguous 131072 floats
  float s = 0.f, ss = 0.f;
  int t = threadIdx.x;
  const float4* p4 = reinterpret_cast<const float4*>(p);
  for (int i = t; i < (32 * S_) / 4; i += 256) {
    float4 v = p4[i];
    s += v.x + v.y + v.z + v.w;
    ss += v.x * v.x + v.y * v.y + v.z * v.z + v.w * v.w;
  }
  for (int m = 1; m < 64; m <<= 1) {
    s += __shfl_xor(s, m, 64);
    ss += __shfl_xor(ss, m, 64);
  }
  __shared__ float rs[4], rss[4];
  int w = t >> 6;
  if ((t & 63) == 0) { rs[w] = s; rss[w] = ss; }
  __syncthreads();
  if (t == 0) {
    float S1 = rs[0] + rs[1] + rs[2] + rs[3];
    float S2 = rss[0] + rss[1] + rss[2] + rss[3];
    float inv = 1.f / (32.f * S_);
    float mu = S1 * inv;
    float var = S2 * inv - mu * mu;
    stats[bg] = mu;
    stats[32 + bg] = rsqrtf(var + 1e-5f);
  }
}

// ---------------- Weight fp32 -> bf16 ----------------
__global__ __launch_bounds__(256) void k_wconv(const float* __restrict__ wq,
                                               const float* __restrict__ wp,
                                               short* __restrict__ oq,
                                               short* __restrict__ op) {
  int i = (blockIdx.x * 256 + threadIdx.x) * 4;  // total 262144 elements
  const int n1 = 768 * 256;
  const float* src = (i < n1) ? (wq + i) : (wp + (i - n1));
  short* dst = (i < n1) ? (oq + i) : (op + (i - n1));
  float4 v = *reinterpret_cast<const float4*>(src);
  short4v o;
  o[0] = f2bf(v.x); o[1] = f2bf(v.y); o[2] = f2bf(v.z); o[3] = f2bf(v.w);
  *reinterpret_cast<short4v*>(dst) = o;
}

// ---------------- GN apply + transpose to xn_t[b][s][c] bf16 ----------------
__global__ __launch_bounds__(256) void k_gn_apply(const float* __restrict__ x,
                                                  const float* __restrict__ gw,
                                                  const float* __restrict__ gb,
                                                  const float* __restrict__ stats,
                                                  short* __restrict__ xnt) {
  int st = blockIdx.x;  // s tile (64)
  int ct = blockIdx.y;  // c tile (4)
  int b = blockIdx.z;
  int t = threadIdx.x;
  __shared__ short T[64 * 72];  // [s][c] padded
  int c0 = ct * 64, s0 = st * 64;
  int r4 = t >> 4;   // 0..15
  int f4 = t & 15;   // float4 col within 64
  for (int p = 0; p < 4; p++) {
    int r = p * 16 + r4;       // c_local
    int c = c0 + r;
    float mu = stats[b * 8 + (c >> 5)];
    float ri = stats[32 + b * 8 + (c >> 5)];
    float A = gw[c] * ri;
    float Bb = gb[c] - mu * A;
    float4 v = *reinterpret_cast<const float4*>(x + ((size_t)(b * C_ + c)) * S_ + s0 + f4 * 4);
    int sb = f4 * 4;
    T[(sb + 0) * 72 + r] = f2bf(v.x * A + Bb);
    T[(sb + 1) * 72 + r] = f2bf(v.y * A + Bb);
    T[(sb + 2) * 72 + r] = f2bf(v.z * A + Bb);
    T[(sb + 3) * 72 + r] = f2bf(v.w * A + Bb);
  }
  __syncthreads();
  for (int it = 0; it < 2; it++) {
    int cch = t + it * 256;  // 0..511
    int sl = cch >> 3, c8 = cch & 7;
    short8 v = *reinterpret_cast<short8*>(&T[sl * 72 + c8 * 8]);
    *reinterpret_cast<short8*>(xnt + ((size_t)(b * S_ + s0 + sl)) * C_ + c0 + c8 * 8) = v;
  }
}

// ---------------- GEMM: C[o][s] = W[o][:] . Xt[s][:]  (TN, bf16 MFMA) -------
// MODE 0: qkv (M=768): writes q_sd/k_sd transposed [bh][s][d], v_ds [bh][d][s]
// MODE 1: proj (M=256): writes fp32 out = acc + bias + residual
template <int MODE>
__global__ __launch_bounds__(256) void k_gemm(const short* __restrict__ Wbf,
                                              const short* __restrict__ Xt,
                                              const float* __restrict__ bias,
                                              const float* __restrict__ xres,
                                              short* __restrict__ q_sd,
                                              short* __restrict__ k_sd,
                                              short* __restrict__ v_ds,
                                              float* __restrict__ outp) {
  int tn = blockIdx.x;  // s tile (32)
  int tm = blockIdx.y;  // o tile
  int b = blockIdx.z;
  int t = threadIdx.x;
  __shared__ short lds[4 * 64 * 72];  // 36864 B; reused for epilogue transpose
  short* Al = lds;            // [128][40]
  short* Bl = lds + 128 * 40; // [128][40]
  int w = t >> 6, lane = t & 63;
  int wr = w >> 1, wc = w & 1;
  int l15 = lane & 15, l4 = lane >> 4;

  f32x4 acc[4][4];
  for (int m = 0; m < 4; m++)
    for (int n = 0; n < 4; n++)
      for (int j = 0; j < 4; j++) acc[m][n][j] = 0.f;

  const short* Arow = Wbf + (size_t)(tm * 128) * 256;
  const short* Brow = Xt + ((size_t)b * S_ + tn * 128) * 256;

  for (int kk = 0; kk < 256; kk += 32) {
    __syncthreads();
    for (int i = 0; i < 2; i++) {
      int cch = t + i * 256;  // 0..511
      int r = cch >> 2, c4 = cch & 3;
      short8 va = *reinterpret_cast<const short8*>(Arow + (size_t)r * 256 + kk + c4 * 8);
      *reinterpret_cast<short8*>(&Al[r * 40 + c4 * 8]) = va;
      short8 vb = *reinterpret_cast<const short8*>(Brow + (size_t)r * 256 + kk + c4 * 8);
      *reinterpret_cast<short8*>(&Bl[r * 40 + c4 * 8]) = vb;
    }
    __syncthreads();
    short8 af[4], bf[4];
    for (int mt = 0; mt < 4; mt++)
      af[mt] = *reinterpret_cast<short8*>(&Al[(wr * 64 + mt * 16 + l15) * 40 + l4 * 8]);
    for (int nt = 0; nt < 4; nt++)
      bf[nt] = *reinterpret_cast<short8*>(&Bl[(wc * 64 + nt * 16 + l15) * 40 + l4 * 8]);
    for (int mt = 0; mt < 4; mt++)
      for (int nt = 0; nt < 4; nt++)
        acc[mt][nt] = __builtin_amdgcn_mfma_f32_16x16x32_bf16(af[mt], bf[nt], acc[mt][nt], 0, 0, 0);
  }
  __syncthreads();

  if (MODE == 0) {
    int o_base = tm * 128 + wr * 64;  // 64-aligned -> single (t,h) per wave
    int tt = o_base >> 8;
    int h = (o_base >> 6) & 3;
    int s_base = tn * 128 + wc * 64;
    int bh = b * NH_ + h;
    if (tt == 2) {
      for (int mt = 0; mt < 4; mt++)
        for (int nt = 0; nt < 4; nt++)
          for (int i = 0; i < 4; i++) {
            int o = o_base + mt * 16 + l4 * 4 + i;
            int dd = o & 63;
            int s = s_base + nt * 16 + l15;
            float val = acc[mt][nt][i] + bias[o];
            v_ds[((size_t)bh * HD_ + dd) * S_ + s] = f2bf(val);
          }
    } else {
      short* T = lds + w * (64 * 72);  // per-wave region
      for (int mt = 0; mt < 4; mt++)
        for (int nt = 0; nt < 4; nt++)
          for (int i = 0; i < 4; i++) {
            int o = o_base + mt * 16 + l4 * 4 + i;
            int dd = mt * 16 + l4 * 4 + i;
            int sl = nt * 16 + l15;
            float val = acc[mt][nt][i] + bias[o];
            T[sl * 72 + dd] = f2bf(val);
          }
      short* dst = (tt == 0) ? q_sd : k_sd;
      for (int it = 0; it < 8; it++) {
        int cch = lane + it * 64;  // 0..511
        int sl = cch >> 3, c8 = cch & 7;
        short8 v = *reinterpret_cast<short8*>(&T[sl * 72 + c8 * 8]);
        *reinterpret_cast<short8*>(dst + ((size_t)bh * S_ + s_base + sl) * HD_ + c8 * 8) = v;
      }
    }
  } else {
    for (int mt = 0; mt < 4; mt++) {
      int o = tm * 128 + wr * 64 + mt * 16 + l4 * 4;
      for (int nt = 0; nt < 4; nt++) {
        int s = tn * 128 + wc * 64 + nt * 16 + l15;
        for (int i = 0; i < 4; i++) {
          size_t off = ((size_t)(b * C_ + o + i)) * S_ + s;
          outp[off] = acc[mt][nt][i] + bias[o + i] + xres[off];
        }
      }
    }
  }
}

// ---------------- Flash attention ----------------
__global__ __launch_bounds__(256) void k_attn(const short* __restrict__ q_sd,
                                              const short* __restrict__ k_sd,
                                              const short* __restrict__ v_ds,
                                              short* __restrict__ ao) {
  int qt = blockIdx.x;  // 0..63
  int bh = blockIdx.y;  // 0..15
  int t = threadIdx.x, w = t >> 6, lane = t & 63;
  int l15 = lane & 15, l4 = lane >> 4;
  __shared__ short Kl[64 * 72];     // [s_k][d] padded
  __shared__ short Vl[64 * 72];     // [d][s_k] padded
  __shared__ short Pl[4 * 16 * 72]; // per-wave P [q][k] padded

  // Q fragments (wave rows qt*64 + w*16 .. +16), scale 1/sqrt(64) folded in
  int qrow = qt * 64 + w * 16 + l15;
  const short* qp = q_sd + ((size_t)bh * S_ + qrow) * HD_;
  short8 qf[2];
  for (int ks = 0; ks < 2; ks++) {
    short8 v = *reinterpret_cast<const short8*>(qp + ks * 32 + l4 * 8);
    for (int j = 0; j < 8; j++) v[j] = f2bf(bf2f(v[j]) * 0.125f);
    qf[ks] = v;
  }

  f32x4 Ofrag[4];
  for (int c2 = 0; c2 < 4; c2++)
    for (int j = 0; j < 4; j++) Ofrag[c2][j] = 0.f;
  float m_run[4] = {-1e30f, -1e30f, -1e30f, -1e30f};
  float l_run[4] = {0.f, 0.f, 0.f, 0.f};

  const short* kbase = k_sd + (size_t)bh * S_ * HD_;
  const short* vbase = v_ds + (size_t)bh * HD_ * S_;
  short* Pw = Pl + w * 16 * 72;

  for (int kt = 0; kt < 64; kt++) {
    __syncthreads();
    for (int i = 0; i < 2; i++) {
      int cch = t + i * 256;  // 0..511
      int sl = cch >> 3, c8 = cch & 7;
      short8 kv = *reinterpret_cast<const short8*>(kbase + (size_t)kt * 64 * HD_ + cch * 8);
      *reinterpret_cast<short8*>(&Kl[sl * 72 + c8 * 8]) = kv;
      short8 vv = *reinterpret_cast<const short8*>(vbase + (size_t)sl * S_ + kt * 64 + c8 * 8);
      *reinterpret_cast<short8*>(&Vl[sl * 72 + c8 * 8]) = vv;
    }
    __syncthreads();

    // S = Q K^T  (16 q-rows x 64 k-cols per wave)
    f32x4 sf[4];
    for (int ct = 0; ct < 4; ct++)
      for (int j = 0; j < 4; j++) sf[ct][j] = 0.f;
    for (int ct = 0; ct < 4; ct++)
      for (int ks = 0; ks < 2; ks++) {
        short8 kf = *reinterpret_cast<short8*>(&Kl[(ct * 16 + l15) * 72 + ks * 32 + l4 * 8]);
        sf[ct] = __builtin_amdgcn_mfma_f32_16x16x32_bf16(qf[ks], kf, sf[ct], 0, 0, 0);
      }

    // online softmax (row = 4*l4 + i)
    float mt_[4];
    for (int i = 0; i < 4; i++) {
      float m = fmaxf(fmaxf(sf[0][i], sf[1][i]), fmaxf(sf[2][i], sf[3][i]));
      for (int d = 1; d < 16; d <<= 1) m = fmaxf(m, __shfl_xor(m, d, 16));
      mt_[i] = m;
    }
    float alpha[4];
    for (int i = 0; i < 4; i++) {
      float mn = fmaxf(m_run[i], mt_[i]);
      alpha[i] = __expf(m_run[i] - mn);
      m_run[i] = mn;
    }
    float pv[4][4];
    float rs[4] = {0.f, 0.f, 0.f, 0.f};
    for (int ct = 0; ct < 4; ct++)
      for (int i = 0; i < 4; i++) {
        float p = __expf(sf[ct][i] - m_run[i]);
        pv[ct][i] = p;
        rs[i] += p;
      }
    for (int i = 0; i < 4; i++) {
      for (int d = 1; d < 16; d <<= 1) rs[i] += __shfl_xor(rs[i], d, 16);
      l_run[i] = l_run[i] * alpha[i] + rs[i];
    }
    for (int c2 = 0; c2 < 4; c2++)
      for (int i = 0; i < 4; i++) Ofrag[c2][i] *= alpha[i];

    // P -> LDS (wave-private)
    for (int ct = 0; ct < 4; ct++)
      for (int i = 0; i < 4; i++)
        Pw[(l4 * 4 + i) * 72 + ct * 16 + l15] = f2bf(pv[ct][i]);

    // O += P V
    for (int ks = 0; ks < 2; ks++) {
      short8 pf = *reinterpret_cast<short8*>(&Pw[l15 * 72 + ks * 32 + l4 * 8]);
      for (int c2 = 0; c2 < 4; c2++) {
        short8 vf = *reinterpret_cast<short8*>(&Vl[(c2 * 16 + l15) * 72 + ks * 32 + l4 * 8]);
        Ofrag[c2] = __builtin_amdgcn_mfma_f32_16x16x32_bf16(pf, vf, Ofrag[c2], 0, 0, 0);
      }
    }
  }

  // epilogue: normalize, write ao[b][s][c] bf16
  int h = bh & 3, b = bh >> 2;
  for (int i = 0; i < 4; i++) {
    float inv = 1.f / l_run[i];
    int s = qt * 64 + w * 16 + l4 * 4 + i;
    for (int c2 = 0; c2 < 4; c2++) {
      int c = h * 64 + c2 * 16 + l15;
      ao[((size_t)(b * S_ + s)) * C_ + c] = f2bf(Ofrag[c2][i] * inv);
    }
  }
}

extern "C" void kernel_launch(void* const* d_in, const int* in_sizes, int n_in,
                              void* d_out, int out_size, void* d_ws, size_t ws_size,
                              hipStream_t stream) {
  const float* x      = (const float*)d_in[0];
  const float* gn_w   = (const float*)d_in[1];
  const float* gn_b   = (const float*)d_in[2];
  const float* qkv_w  = (const float*)d_in[3];
  const float* qkv_b  = (const float*)d_in[4];
  const float* proj_w = (const float*)d_in[5];
  const float* proj_b = (const float*)d_in[6];
  char* ws = (char*)d_ws;
  float* stats = (float*)(ws + 0);         // mu[32], rinv[32]
  short* wqkv  = (short*)(ws + 4096);      // 768*256 bf16
  short* wproj = (short*)(ws + 397312);    // 256*256 bf16
  short* xnt   = (short*)(ws + 528384);    // [4][4096][256] bf16
  short* q_sd  = (short*)(ws + 8916992);   // [16][4096][64] bf16
  short* k_sd  = (short*)(ws + 17305600);  // [16][4096][64] bf16
  short* v_ds  = (short*)(ws + 25694208);  // [16][64][4096] bf16
  short* ao    = (short*)(ws + 34082816);  // [4][4096][256] bf16
  float* outp  = (float*)d_out;

  k_gn_stats<<<32, 256, 0, stream>>>(x, stats);
  k_wconv<<<256, 256, 0, stream>>>(qkv_w, proj_w, wqkv, wproj);
  k_gn_apply<<<dim3(64, 4, 4), 256, 0, stream>>>(x, gn_w, gn_b, stats, xnt);
  k_gemm<0><<<dim3(32, 6, 4), 256, 0, stream>>>(wqkv, xnt, qkv_b, nullptr, q_sd, k_sd, v_ds, nullptr);
  k_attn<<<dim3(64, 16), 256, 0, stream>>>(q_sd, k_sd, v_ds, ao);
  k_gemm<1><<<dim3(32, 2, 4), 256, 0, stream>>>(wproj, ao, proj_b, x, nullptr, nullptr, nullptr, outp);
}